// Round 8
// baseline (104.248 us; speedup 1.0000x reference)
//
#include <hip/hip_runtime.h>

#define NK 21      // classes
#define NC 256     // channels
#define NSRC 64    // source h/w
#define NOUT 256   // mask h/w
#define NB 8       // batch
#define NSL 256    // producer slices per image: 64 rows x 4 column-quarters
#define NG 8       // finalA slice-groups (NSL/32 per group)
#define EPS 1e-6f

// Native LDS fp32 atomic add (ds_add_f32). Plain atomicAdd(float*) lowers to
// a CAS loop — that was the invariant ~44us in R4/R5.
__device__ __forceinline__ void lds_fadd(float* p, float v) {
  __hip_atomic_fetch_add(p, v, __ATOMIC_RELAXED, __HIP_MEMORY_SCOPE_WORKGROUP);
}

// ---------------------------------------------------------------------------
// Main kernel. Grid (64, NB, 4): (source row r0, image b, column-quarter z).
// 2048 blocks = 8/CU — R7's main was TLP-starved at 4/CU with all pipes idle.
// Phase 0: prefetch this thread's 16 feats floats (4 named float4).
// Phase 1: bilinear-adjoint weights W[21][16] in LDS (ds_add_f32) from mask
//          pixels y in [4r0-2, 4r0+5], x in [64z-2, 64z+65] (68-wide window
//          = exactly the x whose taps can land in source cols [16z,16z+16)).
// Phase 2: thread = channel; acc[21] via LDS-broadcast float4 reads.
// Epilogue: plain coalesced stores to psum[B][NSL][K][C] — no atomics.
// ---------------------------------------------------------------------------
__global__ __launch_bounds__(256, 4)
void proto_main(const float* __restrict__ feats,
                const int* __restrict__ masks,
                float* __restrict__ psum,   // [B][NSL][K][C]
                float* __restrict__ pcnt) { // [B][NSL][K]
  __shared__ __align__(16) float Wl[NK * 16];
  __shared__ int hist[NK];

  const int tid = threadIdx.x;
  const int r0 = blockIdx.x;  // source row 0..63
  const int b = blockIdx.y;   // image
  const int z = blockIdx.z;   // column quarter 0..3

  // ---- Phase 0: early feats prefetch (named regs) ----
  const float4* fbase = (const float4*)(
      feats + ((size_t)(b * NC + tid) << 12) + (size_t)r0 * 64 + 16 * z);
  const float4 f0 = fbase[0], f1 = fbase[1], f2 = fbase[2], f3 = fbase[3];

  for (int i = tid; i < NK * 16; i += 256) Wl[i] = 0.f;
  if (tid < NK) hist[tid] = 0;
  __syncthreads();

  // ---- Phase 1 ----
  const int ylo = 4 * r0 - 2;     // may be <0; masked per pixel
  const int xbase = 64 * z - 2;   // may be <0 / overshoot; masked per pixel
  // npix = 8 rows x 68 cols = 544 (constant -> no runtime div)
  for (int i = tid; i < 544; i += 256) {
    const int x = xbase + i % 68;
    const int y = ylo + i / 68;
    if ((unsigned)(x | y) < 256u) {  // both in [0,255]
      const int lbl = masks[((size_t)b * NOUT + y) * NOUT + x];
      if ((unsigned)lbl < NK) {
        // src = 0.25*t - 0.375 (half-pixel 4x); taps j0, j0+1, clamped
        const int ry = y >> 2, py = y & 3;
        const int j0y = (py < 2) ? ry - 1 : ry;
        const float fy = (py == 0) ? 0.625f : (py == 1) ? 0.875f
                       : (py == 2) ? 0.125f : 0.375f;
        const int rx = x >> 2, px = x & 3;
        const int j0x = (px < 2) ? rx - 1 : rx;
        const float fx = (px == 0) ? 0.625f : (px == 1) ? 0.875f
                       : (px == 2) ? 0.125f : 0.375f;

        const int cx0 = (j0x < 0) ? 0 : j0x;
        const int cx1 = (j0x + 1 > NSRC - 1) ? NSRC - 1 : j0x + 1;
        const float wx0 = 1.f - fx, wx1 = fx;
        const int ry0 = (j0y < 0) ? 0 : j0y;
        const int ry1 = (j0y + 1 > NSRC - 1) ? NSRC - 1 : j0y + 1;
        const float wy0 = 1.f - fy, wy1 = fy;

        float* Wk = &Wl[lbl * 16];
        if (ry0 == r0) {
          if ((cx0 >> 4) == z) lds_fadd(&Wk[cx0 & 15], wy0 * wx0);
          if ((cx1 >> 4) == z) lds_fadd(&Wk[cx1 & 15], wy0 * wx1);
        }
        if (ry1 == r0) {
          if ((cx0 >> 4) == z) lds_fadd(&Wk[cx0 & 15], wy1 * wx0);
          if ((cx1 >> 4) == z) lds_fadd(&Wk[cx1 & 15], wy1 * wx1);
        }
        if (y >= 4 * r0 && y < 4 * r0 + 4 && (x >> 6) == z)
          atomicAdd(&hist[lbl], 1);  // int: native ds_add
      }
    }
  }
  __syncthreads();

  // ---- Phase 2: acc[k] = sum_s W[k][s] * F[s] (16 s per quarter) ----
  float acc[NK];
  const float4* wb = (const float4*)Wl;
#pragma unroll
  for (int k = 0; k < NK; ++k) {
    const float4 w0 = wb[k * 4 + 0], w1 = wb[k * 4 + 1];
    const float4 w2 = wb[k * 4 + 2], w3 = wb[k * 4 + 3];
    float a = 0.f;
    a = fmaf(f0.x, w0.x, a); a = fmaf(f0.y, w0.y, a);
    a = fmaf(f0.z, w0.z, a); a = fmaf(f0.w, w0.w, a);
    a = fmaf(f1.x, w1.x, a); a = fmaf(f1.y, w1.y, a);
    a = fmaf(f1.z, w1.z, a); a = fmaf(f1.w, w1.w, a);
    a = fmaf(f2.x, w2.x, a); a = fmaf(f2.y, w2.y, a);
    a = fmaf(f2.z, w2.z, a); a = fmaf(f2.w, w2.w, a);
    a = fmaf(f3.x, w3.x, a); a = fmaf(f3.y, w3.y, a);
    a = fmaf(f3.z, w3.z, a); a = fmaf(f3.w, w3.w, a);
    acc[k] = a;
  }

  // ---- Epilogue: plain coalesced stores ----
  const int sl = r0 * 4 + z;  // 0..255
  float* dst = psum + ((size_t)(b * NSL + sl) * NK) * NC + tid;
#pragma unroll
  for (int k = 0; k < NK; ++k) dst[k * NC] = acc[k];
  if (tid < NK) pcnt[(size_t)(b * NSL + sl) * NK + tid] = (float)hist[tid];
}

// ---------------------------------------------------------------------------
// Finalize A: grid (NK, NB, NG) = 1344 blocks; each reduces 32 slices.
// ---------------------------------------------------------------------------
__global__ __launch_bounds__(256)
void proto_finalA(const float* __restrict__ psum,
                  const float* __restrict__ pcnt,
                  float* __restrict__ psum2,   // [B][NG][K][C]
                  float* __restrict__ pcnt2) { // [B][NG][K]
  const int k = blockIdx.x;   // 0..20
  const int b = blockIdx.y;   // 0..7
  const int g = blockIdx.z;   // 0..7
  const int c = threadIdx.x;  // 0..255
  const int sl0 = g * 32;
  float s = 0.f, cnt = 0.f;
#pragma unroll
  for (int j = 0; j < 32; ++j) {
    s += psum[((size_t)(b * NSL + sl0 + j) * NK + k) * NC + c];  // coalesced
    cnt += pcnt[(size_t)(b * NSL + sl0 + j) * NK + k];           // uniform
  }
  psum2[((size_t)(b * NG + g) * NK + k) * NC + c] = s;
  if (c == 0) pcnt2[(size_t)(b * NG + g) * NK + k] = cnt;
}

// ---------------------------------------------------------------------------
// Finalize B: grid (NK); L2-hot 1.4 MB.
// out[k][c] = (1/8) sum_b [sum_g psum2] / (sum_g pcnt2 + eps)
// ---------------------------------------------------------------------------
__global__ __launch_bounds__(256)
void proto_finalB(const float* __restrict__ psum2,
                  const float* __restrict__ pcnt2,
                  float* __restrict__ out) {
  const int k = blockIdx.x;
  const int c = threadIdx.x;
  float a = 0.f;
#pragma unroll
  for (int b = 0; b < NB; ++b) {
    float s = 0.f, cnt = 0.f;
#pragma unroll
    for (int g = 0; g < NG; ++g) {
      s += psum2[((size_t)(b * NG + g) * NK + k) * NC + c];
      cnt += pcnt2[(size_t)(b * NG + g) * NK + k];
    }
    a += s / (cnt + EPS);
  }
  out[(size_t)k * NC + c] = a * 0.125f;
}

extern "C" void kernel_launch(void* const* d_in, const int* in_sizes, int n_in,
                              void* d_out, int out_size, void* d_ws, size_t ws_size,
                              hipStream_t stream) {
  const float* feats = (const float*)d_in[0];
  const int* masks = (const int*)d_in[1];
  float* out = (float*)d_out;

  // ws: psum [8][256][21][256] (44.0 MB) | pcnt [8][256][21] (172 KB)
  //   | psum2 [8][8][21][256] (1.38 MB)  | pcnt2 [8][8][21] (5.4 KB)
  // All regions fully overwritten before read; no memset needed.
  float* psum = (float*)d_ws;
  float* pcnt = psum + (size_t)NB * NSL * NK * NC;
  float* psum2 = pcnt + (size_t)NB * NSL * NK;
  float* pcnt2 = psum2 + (size_t)NB * NG * NK * NC;

  proto_main<<<dim3(64, NB, 4), 256, 0, stream>>>(feats, masks, psum, pcnt);
  proto_finalA<<<dim3(NK, NB, NG), 256, 0, stream>>>(psum, pcnt, psum2, pcnt2);
  proto_finalB<<<dim3(NK), 256, 0, stream>>>(psum2, pcnt2, out);
}